// Round 1
// baseline (105.007 us; speedup 1.0000x reference)
//
#include <hip/hip_runtime.h>
#include <math.h>

#define NPIX 1024
#define NW 11
#define NL 8
#define NSTATE 2048
#define TPB 256

__global__ __launch_bounds__(TPB) void pqc_kernel(
    const float* __restrict__ image,    // (B, 1024)
    const float* __restrict__ label,    // (B,)
    const float* __restrict__ weights,  // (8, 11, 3)
    float* __restrict__ out)            // (B, 1024)
{
    __shared__ float sRe[NSTATE];
    __shared__ float sIm[NSTATE];
    __shared__ float sU[NL * NW * 8];
    __shared__ float sRed[4];

    const int b   = blockIdx.x;
    const int tid = threadIdx.x;

    // ---- 1. Rot gate matrices (weights-only, computed per block; cheap) ----
    if (tid < NL * NW) {
        const float* w = weights + tid * 3;
        const float PI = 3.14159265358979323846f;
        float phi   = PI * tanhf(w[0]);
        float theta = PI * tanhf(w[1]);
        float omega = PI * tanhf(w[2]);
        float ct = cosf(0.5f * theta), st = sinf(0.5f * theta);
        float a  = 0.5f * (phi + omega);
        float bb = 0.5f * (phi - omega);
        float ca = cosf(a), sa = sinf(a);
        float cb = cosf(bb), sb = sinf(bb);
        float* U = sU + tid * 8;
        // U00 = ep*c = (ca - i sa)*ct
        U[0] =  ca * ct; U[1] = -sa * ct;
        // U01 = -em*s = -(cb + i sb)*st
        U[2] = -cb * st; U[3] = -sb * st;
        // U10 = conj(em)*s = (cb - i sb)*st
        U[4] =  cb * st; U[5] = -sb * st;
        // U11 = conj(ep)*c = (ca + i sa)*ct
        U[6] =  ca * ct; U[7] =  sa * ct;
    }

    // ---- 2. load image (float4, coalesced), compute norm ----
    const float4* img4 = (const float4*)(image + (size_t)b * NPIX);
    float4 v = img4[tid];
    float ss = v.x * v.x + v.y * v.y + v.z * v.z + v.w * v.w;
    #pragma unroll
    for (int off = 32; off >= 1; off >>= 1) ss += __shfl_down(ss, off);
    int lane = tid & 63, wv = tid >> 6;
    if (lane == 0) sRed[wv] = ss;
    __syncthreads();
    float inv = 1.0f / sqrtf(sRed[0] + sRed[1] + sRed[2] + sRed[3]);

    // ---- 3. init state: even flat indices get psi, everything else 0 ----
    {
        int base = tid * 8;  // thread covers amplitudes [8t, 8t+8)
        sRe[base + 0] = v.x * inv; sIm[base + 0] = 0.f;
        sRe[base + 1] = 0.f;       sIm[base + 1] = 0.f;
        sRe[base + 2] = v.y * inv; sIm[base + 2] = 0.f;
        sRe[base + 3] = 0.f;       sIm[base + 3] = 0.f;
        sRe[base + 4] = v.z * inv; sIm[base + 4] = 0.f;
        sRe[base + 5] = 0.f;       sIm[base + 5] = 0.f;
        sRe[base + 6] = v.w * inv; sIm[base + 6] = 0.f;
        sRe[base + 7] = 0.f;       sIm[base + 7] = 0.f;
    }
    __syncthreads();

    // ---- 4. RX(label) on wire 10 (stride 1) ----
    {
        float lab = label[b];
        float cl = cosf(0.5f * lab), sl = sinf(0.5f * lab);
        #pragma unroll
        for (int kk = 0; kk < 4; ++kk) {
            int p = tid + kk * TPB;
            int i0 = 2 * p, i1 = i0 + 1;
            float r0 = sRe[i0], m0 = sIm[i0], r1 = sRe[i1], m1 = sIm[i1];
            sRe[i0] =  cl * r0 + sl * m1;
            sIm[i0] =  cl * m0 - sl * r1;
            sRe[i1] =  sl * m0 + cl * r1;
            sIm[i1] = -sl * r0 + cl * m1;
        }
    }
    __syncthreads();

    // ---- 5. layers ----
    for (int l = 0; l < NL; ++l) {
        // 5a. Rot on each wire q (stride = 2^(10-q))
        for (int q = 0; q < NW; ++q) {
            const float* U = &sU[(l * NW + q) * 8];
            float u00r = U[0], u00i = U[1], u01r = U[2], u01i = U[3];
            float u10r = U[4], u10i = U[5], u11r = U[6], u11i = U[7];
            int k = 10 - q;
            int s = 1 << k;
            #pragma unroll
            for (int kk = 0; kk < 4; ++kk) {
                int p = tid + kk * TPB;
                int low = p & (s - 1);
                int i0 = ((p >> k) << (k + 1)) | low;
                int i1 = i0 + s;
                float r0 = sRe[i0], m0 = sIm[i0], r1 = sRe[i1], m1 = sIm[i1];
                sRe[i0] = u00r * r0 - u00i * m0 + u01r * r1 - u01i * m1;
                sIm[i0] = u00r * m0 + u00i * r0 + u01r * m1 + u01i * r1;
                sRe[i1] = u10r * r0 - u10i * m0 + u11r * r1 - u11i * m1;
                sIm[i1] = u10r * m0 + u10i * r0 + u11r * m1 + u11i * r1;
            }
            __syncthreads();
        }
        // 5b. CNOT ring collapsed to one permutation (CNOTs are basis perms):
        //     final[i] = state[ sigma_0(sigma_1(...sigma_10(i))) ]
        int r = l % (NW - 1) + 1;
        float vr[8], vi[8];
        #pragma unroll
        for (int kk = 0; kk < 8; ++kk) {
            int i = tid + kk * TPB;
            int j = i;
            #pragma unroll
            for (int q = NW - 1; q >= 0; --q) {
                int pc = 10 - q;
                int pt = 10 - ((q + r) % NW);
                j ^= ((j >> pc) & 1) << pt;
            }
            vr[kk] = sRe[j];
            vi[kk] = sIm[j];
        }
        __syncthreads();
        #pragma unroll
        for (int kk = 0; kk < 8; ++kk) {
            int i = tid + kk * TPB;
            sRe[i] = vr[kk];
            sIm[i] = vi[kk];
        }
        __syncthreads();
    }

    // ---- 6. output: probs of even indices * NPIX ----
    #pragma unroll
    for (int kk = 0; kk < 4; ++kk) {
        int p = tid + kk * TPB;
        float r = sRe[2 * p], m = sIm[2 * p];
        out[(size_t)b * NPIX + p] = (r * r + m * m) * (float)NPIX;
    }
}

extern "C" void kernel_launch(void* const* d_in, const int* in_sizes, int n_in,
                              void* d_out, int out_size, void* d_ws, size_t ws_size,
                              hipStream_t stream) {
    const float* image   = (const float*)d_in[0];
    const float* label   = (const float*)d_in[1];
    const float* weights = (const float*)d_in[2];
    float* out = (float*)d_out;
    int batch = in_sizes[1];  // 1024 labels
    pqc_kernel<<<batch, TPB, 0, stream>>>(image, label, weights, out);
}

// Round 2
// 50.822 us; speedup vs baseline: 2.0662x; 2.0662x over previous
//
#include <hip/hip_runtime.h>
#include <math.h>

#define NPIX 1024
#define NW 11
#define NL 8
#define NSTATE 2048
#define TPB 256

// GF(2)-linear LDS address swizzle: XOR bits [7:6] into bits [4:3].
// Chosen with the per-round bit assignments below so every scattered b32
// round hits all 32 banks exactly 2-way (free).
__device__ __forceinline__ int swz(int i) { return i ^ (((i >> 6) & 3) << 3); }

// Apply a 2x2 complex gate to the 4 register pairs differing in local bit LB.
template<int LB>
__device__ __forceinline__ void apply_gate(float (&vr)[8], float (&vi)[8],
                                           const float* __restrict__ U) {
    float u00r = U[0], u00i = U[1], u01r = U[2], u01i = U[3];
    float u10r = U[4], u10i = U[5], u11r = U[6], u11i = U[7];
    #pragma unroll
    for (int s = 0; s < 8; ++s) {
        if (s & (1 << LB)) continue;
        const int s1 = s | (1 << LB);
        float r0 = vr[s], m0 = vi[s], r1 = vr[s1], m1 = vi[s1];
        vr[s]  = u00r*r0 - u00i*m0 + u01r*r1 - u01i*m1;
        vi[s]  = u00r*m0 + u00i*r0 + u01r*m1 + u01i*r1;
        vr[s1] = u10r*r0 - u10i*m0 + u11r*r1 - u11i*m1;
        vi[s1] = u10r*m0 + u10i*r0 + u11r*m1 + u11i*r1;
    }
}

__global__ __launch_bounds__(TPB) void pqc_kernel(
    const float* __restrict__ image,    // (B, 1024)
    const float* __restrict__ label,    // (B,)
    const float* __restrict__ weights,  // (8, 11, 3)
    float* __restrict__ out)            // (B, 1024)
{
    __shared__ __align__(16) float sRe[NSTATE];
    __shared__ __align__(16) float sIm[NSTATE];
    __shared__ __align__(16) float sU[NL * NW * 8];
    __shared__ float sRed[4];

    const int b = blockIdx.x;
    const int t = threadIdx.x;

    // ---- Rot gate matrices (uniform across batch; recomputed per block) ----
    if (t < NL * NW) {
        const float* w = weights + t * 3;
        const float PI = 3.14159265358979323846f;
        float phi   = PI * tanhf(w[0]);
        float theta = PI * tanhf(w[1]);
        float omega = PI * tanhf(w[2]);
        float ct = cosf(0.5f * theta), st = sinf(0.5f * theta);
        float a  = 0.5f * (phi + omega);
        float bb = 0.5f * (phi - omega);
        float ca = cosf(a), sa = sinf(a);
        float cb = cosf(bb), sb = sinf(bb);
        float* U = sU + t * 8;
        U[0] =  ca * ct; U[1] = -sa * ct;   // u00 = ep*c
        U[2] = -cb * st; U[3] = -sb * st;   // u01 = -em*s
        U[4] =  cb * st; U[5] = -sb * st;   // u10 = conj(em)*s
        U[6] =  ca * ct; U[7] =  sa * ct;   // u11 = conj(ep)*c
    }

    // ---- image load + norm ----
    const float4* img4 = (const float4*)(image + (size_t)b * NPIX);
    float4 v = img4[t];
    float ss = v.x * v.x + v.y * v.y + v.z * v.z + v.w * v.w;
    #pragma unroll
    for (int off = 32; off >= 1; off >>= 1) ss += __shfl_down(ss, off);
    if ((t & 63) == 0) sRed[t >> 6] = ss;
    __syncthreads();   // also covers sU writes
    const float inv = 1.0f / sqrtf(sRed[0] + sRed[1] + sRed[2] + sRed[3]);

    // ---- init + RX(label) on wire 10 folded into registers ----
    // amp[2p]   = cos(lab/2) * psi[p]          (real)
    // amp[2p+1] = -i sin(lab/2) * psi[p]       (pure imaginary)
    const float lab = label[b];
    const float cl = cosf(0.5f * lab), sl = sinf(0.5f * lab);
    float vr[8], vi[8];
    {
        float p0 = v.x * inv, p1 = v.y * inv, p2 = v.z * inv, p3 = v.w * inv;
        vr[0] = cl * p0; vi[0] = 0.f;  vr[1] = 0.f; vi[1] = -sl * p0;
        vr[2] = cl * p1; vi[2] = 0.f;  vr[3] = 0.f; vi[3] = -sl * p1;
        vr[4] = cl * p2; vi[4] = 0.f;  vr[5] = 0.f; vi[5] = -sl * p2;
        vr[6] = cl * p3; vi[6] = 0.f;  vr[7] = 0.f; vi[7] = -sl * p3;
    }

    // ---- layers: 4 fused rounds each ----
    for (int l = 0; l < NL; ++l) {
        const float* Ul = &sU[l * NW * 8];

        // ===== round A: local bits = global bits {0,1,2} -> wires 10,9,8 ====
        const int uA = swz(t << 3);   // contiguous 8 amps, b128-friendly
        if (l > 0) {
            float4 a0 = *(const float4*)&sRe[uA];
            float4 a1 = *(const float4*)&sRe[uA + 4];
            float4 b0 = *(const float4*)&sIm[uA];
            float4 b1 = *(const float4*)&sIm[uA + 4];
            vr[0]=a0.x; vr[1]=a0.y; vr[2]=a0.z; vr[3]=a0.w;
            vr[4]=a1.x; vr[5]=a1.y; vr[6]=a1.z; vr[7]=a1.w;
            vi[0]=b0.x; vi[1]=b0.y; vi[2]=b0.z; vi[3]=b0.w;
            vi[4]=b1.x; vi[5]=b1.y; vi[6]=b1.z; vi[7]=b1.w;
        }
        apply_gate<0>(vr, vi, Ul + 10 * 8);
        apply_gate<1>(vr, vi, Ul +  9 * 8);
        apply_gate<2>(vr, vi, Ul +  8 * 8);
        *(float4*)&sRe[uA]     = make_float4(vr[0], vr[1], vr[2], vr[3]);
        *(float4*)&sRe[uA + 4] = make_float4(vr[4], vr[5], vr[6], vr[7]);
        *(float4*)&sIm[uA]     = make_float4(vi[0], vi[1], vi[2], vi[3]);
        *(float4*)&sIm[uA + 4] = make_float4(vi[4], vi[5], vi[6], vi[7]);
        __syncthreads();

        // ===== round B: local bits = global bits {3,4,5} -> wires 7,6,5 ====
        // i = t[2:0] | j<<3 | t[5:3]<<6 | t[7:6]<<9
        {
            const int iB = (t & 7) | (((t >> 3) & 7) << 6) | ((t >> 6) << 9);
            const int uB = swz(iB);
            #pragma unroll
            for (int s = 0; s < 8; ++s) {
                int u = uB ^ (s << 3);           // swz(e3..e5) = identity
                vr[s] = sRe[u]; vi[s] = sIm[u];
            }
            apply_gate<0>(vr, vi, Ul + 7 * 8);
            apply_gate<1>(vr, vi, Ul + 6 * 8);
            apply_gate<2>(vr, vi, Ul + 5 * 8);
            #pragma unroll
            for (int s = 0; s < 8; ++s) {
                int u = uB ^ (s << 3);
                sRe[u] = vr[s]; sIm[u] = vi[s];
            }
        }
        __syncthreads();

        // ===== round C: local bits = global bits {6,7,8} -> wires 4,3,2 ====
        // i = t[5:0] | j<<6 | t[7:6]<<9   (bits[7:6] of base are 0 -> swz(iC)=iC)
        {
            const int uC = (t & 63) | ((t >> 6) << 9);
            #pragma unroll
            for (int s = 0; s < 8; ++s) {
                int u = uC ^ (s << 6) ^ ((s & 3) << 3);   // swz of s<<6
                vr[s] = sRe[u]; vi[s] = sIm[u];
            }
            apply_gate<0>(vr, vi, Ul + 4 * 8);
            apply_gate<1>(vr, vi, Ul + 3 * 8);
            apply_gate<2>(vr, vi, Ul + 2 * 8);
            #pragma unroll
            for (int s = 0; s < 8; ++s) {
                int u = uC ^ (s << 6) ^ ((s & 3) << 3);
                sRe[u] = vr[s]; sIm[u] = vi[s];
            }
        }
        __syncthreads();

        // ===== round D: local bits = global bits {3,9,10}; gates on 9,10
        //       (wires 1,0); CNOT ring folded into the store permutation ====
        // i = t[2:0] | j0<<3 | t[3]<<4 | t[7]<<5 | t[4]<<6 | t[5]<<7 | t[6]<<8
        //     | j1<<9 | j2<<10
        {
            const int iD = (t & 7) | (((t >> 3) & 1) << 4) | (((t >> 7) & 1) << 5)
                         | (((t >> 4) & 1) << 6) | (((t >> 5) & 1) << 7)
                         | (((t >> 6) & 1) << 8);
            const int uD = swz(iD);
            #pragma unroll
            for (int s = 0; s < 8; ++s) {
                int u = uD ^ ((s & 1) << 3) ^ (((s >> 1) & 1) << 9)
                           ^ (((s >> 2) & 1) << 10);
                vr[s] = sRe[u]; vi[s] = sIm[u];
            }
            apply_gate<1>(vr, vi, Ul + 1 * 8);   // bit 9  -> wire 1
            apply_gate<2>(vr, vi, Ul + 0 * 8);   // bit 10 -> wire 0
            // inverse of the composed CNOT permutation (GF(2)-linear):
            // final[m] = state[sigma(m)]  =>  store amp(i) at m = sigma^{-1}(i)
            const int r = l % (NW - 1) + 1;
            int mB = iD, B3 = 1 << 3, B9 = 1 << 9, B10 = 1 << 10;
            #pragma unroll
            for (int q = 0; q < NW; ++q) {
                int pc = 10 - q;
                int qq = q + r; if (qq >= NW) qq -= NW;
                int pt = 10 - qq;
                mB  ^= ((mB  >> pc) & 1) << pt;
                B3  ^= ((B3  >> pc) & 1) << pt;
                B9  ^= ((B9  >> pc) & 1) << pt;
                B10 ^= ((B10 >> pc) & 1) << pt;
            }
            const int um = swz(mB), c3 = swz(B3), c9 = swz(B9), c10 = swz(B10);
            #pragma unroll
            for (int s = 0; s < 8; ++s) {
                int u = um ^ ((s & 1) ? c3 : 0) ^ ((s & 2) ? c9 : 0)
                           ^ ((s & 4) ? c10 : 0);
                sRe[u] = vr[s]; sIm[u] = vi[s];
            }
        }
        __syncthreads();
    }

    // ---- output: probs of even amplitudes * NPIX, coalesced stores ----
    #pragma unroll
    for (int k = 0; k < 4; ++k) {
        int u = swz(2 * t) ^ (k << 9);        // amp index 2t + 512k
        float rr = sRe[u], mm = sIm[u];
        out[(size_t)b * NPIX + (k << 8) + t] = (rr * rr + mm * mm) * (float)NPIX;
    }
}

extern "C" void kernel_launch(void* const* d_in, const int* in_sizes, int n_in,
                              void* d_out, int out_size, void* d_ws, size_t ws_size,
                              hipStream_t stream) {
    const float* image   = (const float*)d_in[0];
    const float* label   = (const float*)d_in[1];
    const float* weights = (const float*)d_in[2];
    float* out = (float*)d_out;
    int batch = in_sizes[1];  // 1024
    pqc_kernel<<<batch, TPB, 0, stream>>>(image, label, weights, out);
}

// Round 3
// 44.218 us; speedup vs baseline: 2.3747x; 1.1493x over previous
//
#include <hip/hip_runtime.h>
#include <math.h>

#define NW 11
#define NL 8
#define NPIX 1024
#define TPB 128

typedef float f2 __attribute__((ext_vector_type(2)));
typedef float f4 __attribute__((ext_vector_type(4)));

// GF(2)-linear LDS swizzle at float2-element granularity:
// XOR elem bits [6:4] into bits [3:1] (spreads 16B quads across banks).
__device__ __forceinline__ int SW(int i) { return i ^ (((i >> 4) & 7) << 1); }

// Store-side composed CNOT permutation for layer with shift r (validated in
// rounds 1-2): ascending q, m ^= ((m>>pc)&1)<<pt, pc=10-q, pt=10-((q+r)%11).
__device__ __forceinline__ int Fmap(int m, int r) {
    #pragma unroll
    for (int q = 0; q < NW; ++q) {
        int pc = 10 - q;
        int qq = q + r; if (qq >= NW) qq -= NW;
        int pt = 10 - qq;
        m ^= ((m >> pc) & 1) << pt;
    }
    return m;
}

// One 2x2 complex gate on 8 register pairs (pairing mask B), packed-f32 form.
// g points at 8 pre-packed f2 coefs: {(u00r,u00r),(-u00i,u00i),(u01r,u01r),
// (-u01i,u01i),(u10r,u10r),(-u10i,u10i),(u11r,u11r),(-u11i,u11i)}.
template<int B>
__device__ __forceinline__ void gate16(f2 (&v)[16], const f2* __restrict__ g) {
    f2 c0 = g[0], c1 = g[1], c2 = g[2], c3 = g[3];
    f2 c4 = g[4], c5 = g[5], c6 = g[6], c7 = g[7];
    #pragma unroll
    for (int s = 0; s < 16; ++s) {
        if (s & B) continue;
        f2 v0 = v[s], v1 = v[s | B];
        f2 w0 = v0.yx, w1 = v1.yx;
        f2 o0 = __builtin_elementwise_fma(c3, w1,
                 __builtin_elementwise_fma(c2, v1,
                  __builtin_elementwise_fma(c1, w0, c0 * v0)));
        f2 o1 = __builtin_elementwise_fma(c7, w1,
                 __builtin_elementwise_fma(c6, v1,
                  __builtin_elementwise_fma(c5, w0, c4 * v0)));
        v[s] = o0; v[s | B] = o1;
    }
}

// ---- kernel 1: 88 Rot gate matrices -> d_ws (weights-only) ----
__global__ void gates_kernel(const float* __restrict__ weights, f2* __restrict__ gw) {
    int t = threadIdx.x;
    if (t < NL * NW) {
        const float* w = weights + t * 3;
        const float PI = 3.14159265358979323846f;
        float phi   = PI * tanhf(w[0]);
        float theta = PI * tanhf(w[1]);
        float omega = PI * tanhf(w[2]);
        float ct = cosf(0.5f * theta), st = sinf(0.5f * theta);
        float a  = 0.5f * (phi + omega), bb = 0.5f * (phi - omega);
        float ca = cosf(a), sa = sinf(a), cb = cosf(bb), sb = sinf(bb);
        float u00r =  ca * ct, u00i = -sa * ct;
        float u01r = -cb * st, u01i = -sb * st;
        float u10r =  cb * st, u10i = -sb * st;
        float u11r =  ca * ct, u11i =  sa * ct;
        f2* g = gw + t * 8;
        g[0] = (f2){u00r, u00r}; g[1] = (f2){-u00i, u00i};
        g[2] = (f2){u01r, u01r}; g[3] = (f2){-u01i, u01i};
        g[4] = (f2){u10r, u10r}; g[5] = (f2){-u10i, u10i};
        g[6] = (f2){u11r, u11r}; g[7] = (f2){-u11i, u11i};
    }
}

// ---- kernel 2: one block (128 thr) per batch element, 16 amps/thread ----
__global__ __launch_bounds__(TPB) void pqc_kernel(
    const float* __restrict__ image, const float* __restrict__ label,
    const f2* __restrict__ gw, float* __restrict__ out)
{
    __shared__ __align__(16) f2 sS[2048];   // state, swizzled identity layout
    __shared__ int sColS[NL * NW];          // SW(F_l(e_p))
    __shared__ int sD16[NL * 16];           // SW of R2 write-offset combos
    __shared__ float sRed[2];

    const int b = blockIdx.x, t = threadIdx.x;

    // image load: 8 floats/thread
    const f4* img4 = (const f4*)(image + (size_t)b * NPIX);
    f4 x0 = img4[2 * t], x1 = img4[2 * t + 1];

    // permutation column table (phase 1)
    if (t < NL * NW) {
        int l = t / NW, p = t % NW;
        sColS[t] = SW(Fmap(1 << p, l + 1));   // r = l%(NW-1)+1 = l+1
    }

    // norm partial
    float ss = x0.x*x0.x + x0.y*x0.y + x0.z*x0.z + x0.w*x0.w
             + x1.x*x1.x + x1.y*x1.y + x1.z*x1.z + x1.w*x1.w;
    #pragma unroll
    for (int off = 32; off >= 1; off >>= 1) ss += __shfl_down(ss, off);
    if ((t & 63) == 0) sRed[t >> 6] = ss;
    __syncthreads();

    // phase 2: R2 write-offset table (XOR combos of columns 0,8,9,10)
    {
        int l = t >> 4, s = t & 15;
        int d = 0;
        if (s & 1) d ^= sColS[l * NW + 0];
        if (s & 2) d ^= sColS[l * NW + 8];
        if (s & 4) d ^= sColS[l * NW + 9];
        if (s & 8) d ^= sColS[l * NW + 10];
        sD16[t] = d;
    }

    const float inv = 1.0f / sqrtf(sRed[0] + sRed[1]);
    const float lab = label[b];
    const float cl = cosf(0.5f * lab), sl = sinf(0.5f * lab);

    // init + RX(wire 10) folded: amp[2p]=(cl*psi,0), amp[2p+1]=(0,-sl*psi)
    {
        const int base = t << 4, key2 = (t & 7) << 1;
        float ps[8] = {x0.x, x0.y, x0.z, x0.w, x1.x, x1.y, x1.z, x1.w};
        #pragma unroll
        for (int j = 0; j < 8; ++j) {
            float p = ps[j] * inv;
            f4 w; w.x = cl * p; w.y = 0.f; w.z = 0.f; w.w = -sl * p;
            *(f4*)&sS[base + ((2 * j) ^ key2)] = w;
        }
    }
    __syncthreads();   // also covers sD16

    f2 v[16];
    for (int l = 0; l < NL; ++l) {
        const f2* G = gw + (size_t)l * NW * 8;

        // ---- R0: amp bits {0,1,2,3} local = wires 10,9,8,7; b128 ----
        {
            const int base = t << 4, key2 = (t & 7) << 1;
            #pragma unroll
            for (int k = 0; k < 8; ++k) {
                f4 w = *(const f4*)&sS[base + ((2 * k) ^ key2)];
                v[2*k] = w.xy; v[2*k+1] = w.zw;
            }
            gate16<1>(v, G + 10 * 8);
            gate16<2>(v, G +  9 * 8);
            gate16<4>(v, G +  8 * 8);
            gate16<8>(v, G +  7 * 8);
            #pragma unroll
            for (int k = 0; k < 8; ++k) {
                f4 w; w.xy = v[2*k]; w.zw = v[2*k+1];
                *(f4*)&sS[base + ((2 * k) ^ key2)] = w;
            }
        }
        __syncthreads();

        // ---- R1: amp bits {4,5,6,7} local = wires 6,5,4,3; b64 ----
        {
            const int base = (t & 15) | ((t >> 4) << 8);
            #pragma unroll
            for (int s = 0; s < 16; ++s)
                v[s] = sS[(base ^ ((s & 7) << 1)) + (s << 4)];
            gate16<1>(v, G + 6 * 8);
            gate16<2>(v, G + 5 * 8);
            gate16<4>(v, G + 4 * 8);
            gate16<8>(v, G + 3 * 8);
            #pragma unroll
            for (int s = 0; s < 16; ++s)
                sS[(base ^ ((s & 7) << 1)) + (s << 4)] = v[s];
        }
        __syncthreads();

        // ---- R2: amp bits {8,9,10} = wires 2,1,0 (+bit0 for b128 reads);
        //      CNOT ring folded into the (swizzled) store permutation ----
        {
            const int base = t << 1;
            const int eb = base ^ (((t >> 3) & 7) << 1);
            #pragma unroll
            for (int k = 0; k < 8; ++k) {
                f4 w = *(const f4*)&sS[eb + (k << 8)];
                v[2*k] = w.xy; v[2*k+1] = w.zw;
            }
            gate16<2>(v, G + 2 * 8);   // bit8  = wire 2
            gate16<4>(v, G + 1 * 8);   // bit9  = wire 1
            gate16<8>(v, G + 0 * 8);   // bit10 = wire 0
            // swMB = SW(F_l(base)) via XOR of swizzled columns (linearity)
            int swMB = 0;
            #pragma unroll
            for (int p = 1; p <= 7; ++p)
                if ((base >> p) & 1) swMB ^= sColS[l * NW + p];
            const int* D = &sD16[l * 16];
            #pragma unroll
            for (int s = 0; s < 16; ++s)
                sS[swMB ^ D[s]] = v[s];
        }
        __syncthreads();
    }

    // ---- output: |amp[2p]|^2 * NPIX, p = t + 128k ----
    {
        const int eb = (2 * t) ^ (((t >> 3) & 7) << 1);
        #pragma unroll
        for (int k = 0; k < 8; ++k) {
            f2 a = sS[eb + (k << 8)];
            out[(size_t)b * NPIX + (k << 7) + t] = (a.x*a.x + a.y*a.y) * (float)NPIX;
        }
    }
}

extern "C" void kernel_launch(void* const* d_in, const int* in_sizes, int n_in,
                              void* d_out, int out_size, void* d_ws, size_t ws_size,
                              hipStream_t stream) {
    const float* image   = (const float*)d_in[0];
    const float* label   = (const float*)d_in[1];
    const float* weights = (const float*)d_in[2];
    float* out = (float*)d_out;
    f2* gw = (f2*)d_ws;   // 88 gates * 8 f2 = 5632 bytes
    int batch = in_sizes[1];  // 1024
    gates_kernel<<<1, TPB, 0, stream>>>(weights, gw);
    pqc_kernel<<<batch, TPB, 0, stream>>>(image, label, gw, out);
}